// Round 5
// baseline (910.070 us; speedup 1.0000x reference)
//
#include <hip/hip_runtime.h>
#include <math.h>

#define BT_TOK 32768
#define D_IN   1024
#define H1D    768
#define H2D    512
#define KCB    512

typedef short bf16x8 __attribute__((ext_vector_type(8)));
typedef _Float16 f16;
typedef _Float16 half8v __attribute__((ext_vector_type(8)));
typedef float f32x4 __attribute__((ext_vector_type(4)));

#define GLDS16(g, l) \
    __builtin_amdgcn_global_load_lds((const __attribute__((address_space(1))) void*)(g), \
                                     (__attribute__((address_space(3))) void*)(l), 16, 0, 0)

__device__ __forceinline__ unsigned short f2bf(float f) {
    union { float f; unsigned u; } v; v.f = f;
    const unsigned r = v.u + 0x7FFFu + ((v.u >> 16) & 1u);
    return (unsigned short)(r >> 16);
}

// split convention: hi = f16(v), lo = f16((v-hi)*2048); v ~= hi + lo/2048
__device__ __forceinline__ void splitf(float v, f16& h, f16& l) {
    h = (f16)v;
    l = (f16)((v - (float)h) * 2048.f);
}

// ---------------------------------------------------------------------------
// Split-FP16 MFMA GEMM, BK=64 (two K32 sub-buffers, 64-B rows -> conflicts
// stay 8-way; GLDS lane order preserved). 128x128 tile, 3 MFMAs per frag pair.
// EPI 0: +bias, write f16 hi/lo pair. EPI 1: VQ tile-argmin.
// ---------------------------------------------------------------------------
template<int EPI>
__global__ __launch_bounds__(256, 2) void sgemm_k(
    const f16* __restrict__ Ah, const f16* __restrict__ Al,
    const f16* __restrict__ Bh, const f16* __restrict__ Bl,
    const float* __restrict__ bias,
    f16* __restrict__ Ch, f16* __restrict__ Cl,
    const float* __restrict__ cnorm,
    float* __restrict__ cand_v, int* __restrict__ cand_i,
    int N, int Kd)
{
    // [2 sub-buffers][128 rows][32 f16] each operand -> 16 KB x4 = 64 KB
    __shared__ __align__(16) f16 sAh[2 * 128 * 32];
    __shared__ __align__(16) f16 sAl[2 * 128 * 32];
    __shared__ __align__(16) f16 sBh[2 * 128 * 32];
    __shared__ __align__(16) f16 sBl[2 * 128 * 32];

    const int t = threadIdx.x;
    const int lane = t & 63, wave = t >> 6;
    const int wm = wave & 1, wn = wave >> 1;
    const int row0 = blockIdx.y * 128, col0 = blockIdx.x * 128;

    f32x4 acc_h[4][4], acc_l[4][4];
#pragma unroll
    for (int i = 0; i < 4; ++i)
#pragma unroll
        for (int j = 0; j < 4; ++j) {
            acc_h[i][j] = (f32x4){0.f, 0.f, 0.f, 0.f};
            acc_l[i][j] = (f32x4){0.f, 0.f, 0.f, 0.f};
        }

    // staging: GLDS instr (kk, j2) covers rows j2*64 + wave*16 + (lane>>2),
    // f16 col kk*32 + (lane&3)*8; LDS dst = kk*8192 + j2*4096 + wave*1024 (B)
    const int srow = wave * 16 + (lane >> 2);
    const int scol = (lane & 3) * 8;

    const f16* gAh = Ah + (size_t)(row0 + srow) * Kd + scol;
    const f16* gAl = Al + (size_t)(row0 + srow) * Kd + scol;
    const f16* gBh = Bh + (size_t)(col0 + srow) * Kd + scol;
    const f16* gBl = Bl + (size_t)(col0 + srow) * Kd + scol;

    const int fr = lane & 15;
    const int fko = (lane >> 4) * 16;   // byte offset in 64-B row

    for (int k0 = 0; k0 < Kd; k0 += 64) {
#pragma unroll
        for (int kk = 0; kk < 2; ++kk)
#pragma unroll
            for (int j2 = 0; j2 < 2; ++j2) {
                const size_t go = (size_t)j2 * 64 * Kd + kk * 32 + k0;
                const int lo = kk * 8192 + j2 * 4096 + wave * 1024;
                GLDS16(gAh + go, (char*)sAh + lo);
                GLDS16(gAl + go, (char*)sAl + lo);
                GLDS16(gBh + go, (char*)sBh + lo);
                GLDS16(gBl + go, (char*)sBl + lo);
            }
        __syncthreads();

#pragma unroll
        for (int kk = 0; kk < 2; ++kk) {
            half8v fah[4], fal[4];
#pragma unroll
            for (int mi = 0; mi < 4; ++mi) {
                const int ao = kk * 8192 + (wm * 64 + mi * 16 + fr) * 64 + fko;
                fah[mi] = *(const half8v*)((char*)sAh + ao);
                fal[mi] = *(const half8v*)((char*)sAl + ao);
            }
#pragma unroll
            for (int ni = 0; ni < 4; ++ni) {
                const int bo = kk * 8192 + (wn * 64 + ni * 16 + fr) * 64 + fko;
                const half8v fbh = *(const half8v*)((char*)sBh + bo);
                const half8v fbl = *(const half8v*)((char*)sBl + bo);
#pragma unroll
                for (int mi = 0; mi < 4; ++mi) {
                    acc_h[mi][ni] = __builtin_amdgcn_mfma_f32_16x16x32_f16(
                        fah[mi], fbh, acc_h[mi][ni], 0, 0, 0);
                    acc_l[mi][ni] = __builtin_amdgcn_mfma_f32_16x16x32_f16(
                        fah[mi], fbl, acc_l[mi][ni], 0, 0, 0);
                    acc_l[mi][ni] = __builtin_amdgcn_mfma_f32_16x16x32_f16(
                        fal[mi], fbh, acc_l[mi][ni], 0, 0, 0);
                }
            }
        }
        __syncthreads();
    }

    const int cR = (lane >> 4) * 4;   // C/D: row = quad*4 + reg, col = lane&15
    const int cC = lane & 15;

    if (EPI == 0) {
#pragma unroll
        for (int ni = 0; ni < 4; ++ni) {
            const int col = col0 + wn * 64 + ni * 16 + cC;
            const float bb = bias[col];
#pragma unroll
            for (int mi = 0; mi < 4; ++mi)
#pragma unroll
                for (int r = 0; r < 4; ++r) {
                    const size_t row = row0 + wm * 64 + mi * 16 + cR + r;
                    const float v = acc_h[mi][ni][r] + acc_l[mi][ni][r] * (1.f / 2048.f) + bb;
                    f16 vh, vl;
                    splitf(v, vh, vl);
                    Ch[row * N + col] = vh;
                    Cl[row * N + col] = vl;
                }
        }
    } else {
#pragma unroll
        for (int mi = 0; mi < 4; ++mi)
#pragma unroll
            for (int r = 0; r < 4; ++r) {
                float bestv = 1e30f;
                int besti = 0;
#pragma unroll
                for (int ni = 0; ni < 4; ++ni) {
                    const int col = col0 + wn * 64 + ni * 16 + cC;
                    const float v = cnorm[col]
                        - 2.f * (acc_h[mi][ni][r] + acc_l[mi][ni][r] * (1.f / 2048.f));
                    if (v < bestv || (v == bestv && col < besti)) { bestv = v; besti = col; }
                }
#pragma unroll
                for (int m = 1; m < 16; m <<= 1) {
                    const float ov = __shfl_xor(bestv, m);
                    const int oi = __shfl_xor(besti, m);
                    if (ov < bestv || (ov == bestv && oi < besti)) { bestv = ov; besti = oi; }
                }
                if (cC == 0) {
                    const size_t row = row0 + wm * 64 + mi * 16 + cR + r;
                    cand_v[row * 8 + blockIdx.x * 2 + wn] = bestv;
                    cand_i[row * 8 + blockIdx.x * 2 + wn] = besti;
                }
            }
    }
}

// ---------------------------------------------------------------------------
// Fallback GEMM1 (round-4 XSPLIT, BK=32) — used only if ws too small for the
// pre-split x buffers. Branch is on ws_size (launch-constant) -> graph-safe.
// ---------------------------------------------------------------------------
__global__ __launch_bounds__(256, 2) void sgemm_x_k(
    const float* __restrict__ Af,
    const f16* __restrict__ Bh, const f16* __restrict__ Bl,
    const float* __restrict__ bias,
    f16* __restrict__ Ch, f16* __restrict__ Cl,
    int N, int Kd)
{
    __shared__ __align__(16) f16 sAh[128 * 32];
    __shared__ __align__(16) f16 sAl[128 * 32];
    __shared__ __align__(16) f16 sBh[128 * 32];
    __shared__ __align__(16) f16 sBl[128 * 32];

    const int t = threadIdx.x;
    const int lane = t & 63, wave = t >> 6;
    const int wm = wave & 1, wn = wave >> 1;
    const int row0 = blockIdx.y * 128, col0 = blockIdx.x * 128;

    f32x4 acc_h[4][4], acc_l[4][4];
#pragma unroll
    for (int i = 0; i < 4; ++i)
#pragma unroll
        for (int j = 0; j < 4; ++j) {
            acc_h[i][j] = (f32x4){0.f, 0.f, 0.f, 0.f};
            acc_l[i][j] = (f32x4){0.f, 0.f, 0.f, 0.f};
        }

    const int sr = t >> 2;
    const int sk8 = (t & 3) * 8;
    const int arow = t >> 1;
    const int ac = (t & 1) * 16;

    const f16* gBh0 = Bh + (size_t)(col0 + sr) * Kd + sk8;
    const f16* gBh1 = Bh + (size_t)(col0 + 64 + sr) * Kd + sk8;
    const f16* gBl0 = Bl + (size_t)(col0 + sr) * Kd + sk8;
    const f16* gBl1 = Bl + (size_t)(col0 + 64 + sr) * Kd + sk8;
    const float* gAf = Af + (size_t)(row0 + arow) * Kd + ac;

    char* dBh0 = (char*)sBh + wave * 1024;
    char* dBh1 = (char*)sBh + 4096 + wave * 1024;
    char* dBl0 = (char*)sBl + wave * 1024;
    char* dBl1 = (char*)sBl + 4096 + wave * 1024;

    const int fr = lane & 15;
    const int fq8 = (lane >> 4) * 8;

    for (int k0 = 0; k0 < Kd; k0 += 32) {
        {
            const float4* gp = (const float4*)(gAf + k0);
#pragma unroll
            for (int h8 = 0; h8 < 2; ++h8) {
                const float4 f0 = gp[h8 * 2];
                const float4 f1 = gp[h8 * 2 + 1];
                const float fv[8] = {f0.x, f0.y, f0.z, f0.w, f1.x, f1.y, f1.z, f1.w};
                f16 hv[8] __attribute__((aligned(16)));
                f16 lv[8] __attribute__((aligned(16)));
#pragma unroll
                for (int i = 0; i < 8; ++i) splitf(fv[i], hv[i], lv[i]);
                *(half8v*)(sAh + arow * 32 + ac + h8 * 8) = *(half8v*)hv;
                *(half8v*)(sAl + arow * 32 + ac + h8 * 8) = *(half8v*)lv;
            }
        }
        GLDS16(gBh0 + k0, dBh0);
        GLDS16(gBh1 + k0, dBh1);
        GLDS16(gBl0 + k0, dBl0);
        GLDS16(gBl1 + k0, dBl1);
        __syncthreads();

        half8v fah[4], fal[4];
#pragma unroll
        for (int mi = 0; mi < 4; ++mi) {
            fah[mi] = *(const half8v*)(sAh + (wm * 64 + mi * 16 + fr) * 32 + fq8);
            fal[mi] = *(const half8v*)(sAl + (wm * 64 + mi * 16 + fr) * 32 + fq8);
        }
#pragma unroll
        for (int ni = 0; ni < 4; ++ni) {
            const half8v fbh = *(const half8v*)(sBh + (wn * 64 + ni * 16 + fr) * 32 + fq8);
            const half8v fbl = *(const half8v*)(sBl + (wn * 64 + ni * 16 + fr) * 32 + fq8);
#pragma unroll
            for (int mi = 0; mi < 4; ++mi) {
                acc_h[mi][ni] = __builtin_amdgcn_mfma_f32_16x16x32_f16(
                    fah[mi], fbh, acc_h[mi][ni], 0, 0, 0);
                acc_l[mi][ni] = __builtin_amdgcn_mfma_f32_16x16x32_f16(
                    fah[mi], fbl, acc_l[mi][ni], 0, 0, 0);
                acc_l[mi][ni] = __builtin_amdgcn_mfma_f32_16x16x32_f16(
                    fal[mi], fbh, acc_l[mi][ni], 0, 0, 0);
            }
        }
        __syncthreads();
    }

    const int cR = (lane >> 4) * 4;
    const int cC = lane & 15;
#pragma unroll
    for (int ni = 0; ni < 4; ++ni) {
        const int col = col0 + wn * 64 + ni * 16 + cC;
        const float bb = bias[col];
#pragma unroll
        for (int mi = 0; mi < 4; ++mi)
#pragma unroll
            for (int r = 0; r < 4; ++r) {
                const size_t row = row0 + wm * 64 + mi * 16 + cR + r;
                const float v = acc_h[mi][ni][r] + acc_l[mi][ni][r] * (1.f / 2048.f) + bb;
                f16 vh, vl;
                splitf(v, vh, vl);
                Ch[row * N + col] = vh;
                Cl[row * N + col] = vl;
            }
    }
}

// ---------------------------------------------------------------------------
// bf16 MFMA GEMM for the decoder (loss path; 2% tolerance). BK=64, two
// K32 sub-buffers (same geometry as sgemm_k).
// ---------------------------------------------------------------------------
template<int EPI>
__global__ __launch_bounds__(256, 2) void mfma_gemm_k(
    const unsigned short* __restrict__ A, const unsigned short* __restrict__ BT,
    const float* __restrict__ bias, unsigned short* __restrict__ Cbf,
    const float* __restrict__ Xref, float* __restrict__ lsum_out,
    const int* __restrict__ gidx, int N, int Kd)
{
    __shared__ __align__(16) unsigned short sA[2 * 128 * 32];
    __shared__ __align__(16) unsigned short sB[2 * 128 * 32];

    const int t = threadIdx.x;
    const int lane = t & 63, wave = t >> 6;
    const int wm = wave & 1, wn = wave >> 1;
    const int row0 = blockIdx.y * 128, col0 = blockIdx.x * 128;

    f32x4 acc[4][4];
#pragma unroll
    for (int i = 0; i < 4; ++i)
#pragma unroll
        for (int j = 0; j < 4; ++j) acc[i][j] = (f32x4){0.f, 0.f, 0.f, 0.f};

    const int srow = wave * 16 + (lane >> 2);
    const int scol = (lane & 3) * 8;

    int ar[2];
    ar[0] = row0 + srow; ar[1] = row0 + 64 + srow;
    if (gidx) { ar[0] = gidx[row0 + srow]; ar[1] = gidx[row0 + 64 + srow]; }

    const int fr = lane & 15;
    const int fko = (lane >> 4) * 16;

    for (int k0 = 0; k0 < Kd; k0 += 64) {
#pragma unroll
        for (int kk = 0; kk < 2; ++kk)
#pragma unroll
            for (int j2 = 0; j2 < 2; ++j2) {
                const int lo = kk * 8192 + j2 * 4096 + wave * 1024;
                GLDS16(A + (size_t)ar[j2] * Kd + kk * 32 + scol + k0, (char*)sA + lo);
                GLDS16(BT + (size_t)(col0 + j2 * 64 + srow) * Kd + kk * 32 + scol + k0,
                       (char*)sB + lo);
            }
        __syncthreads();

#pragma unroll
        for (int kk = 0; kk < 2; ++kk) {
            bf16x8 a[4];
#pragma unroll
            for (int mi = 0; mi < 4; ++mi)
                a[mi] = *(const bf16x8*)((char*)sA + kk * 8192 + (wm * 64 + mi * 16 + fr) * 64 + fko);
#pragma unroll
            for (int ni = 0; ni < 4; ++ni) {
                const bf16x8 b = *(const bf16x8*)((char*)sB + kk * 8192 + (wn * 64 + ni * 16 + fr) * 64 + fko);
#pragma unroll
                for (int mi = 0; mi < 4; ++mi)
                    acc[mi][ni] = __builtin_amdgcn_mfma_f32_16x16x32_bf16(
                        a[mi], b, acc[mi][ni], 0, 0, 0);
            }
        }
        __syncthreads();
    }

    const int cR = (lane >> 4) * 4;
    const int cC = lane & 15;

    if (EPI == 0) {
#pragma unroll
        for (int ni = 0; ni < 4; ++ni) {
            const int col = col0 + wn * 64 + ni * 16 + cC;
            const float bb = bias[col];
#pragma unroll
            for (int mi = 0; mi < 4; ++mi)
#pragma unroll
                for (int r = 0; r < 4; ++r) {
                    const size_t row = row0 + wm * 64 + mi * 16 + cR + r;
                    const float v = fmaxf(acc[mi][ni][r] + bb, 0.f);
                    Cbf[row * N + col] = f2bf(v);
                }
        }
    } else {
        float ls = 0.f;
#pragma unroll
        for (int ni = 0; ni < 4; ++ni) {
            const int col = col0 + wn * 64 + ni * 16 + cC;
            const float bb = bias[col];
#pragma unroll
            for (int mi = 0; mi < 4; ++mi)
#pragma unroll
                for (int r = 0; r < 4; ++r) {
                    const size_t row = row0 + wm * 64 + mi * 16 + cR + r;
                    const float d = acc[mi][ni][r] + bb - Xref[row * N + col];
                    ls = fmaf(d, d, ls);
                }
        }
        __shared__ float red[256];
        red[t] = ls;
        __syncthreads();
        for (int s = 128; s > 0; s >>= 1) {
            if (t < s) red[t] += red[t + s];
            __syncthreads();
        }
        if (t == 0) atomicAdd(lsum_out, red[0]);
    }
}

// ---------------------------------------------------------------------------
// Fused prep: weight splits/transposes/conversions + codebook norms + x split.
// One launch replaces 7 tiny launches.
// ---------------------------------------------------------------------------
__global__ __launch_bounds__(256) void prep_k(
    const float* __restrict__ enc_w1, f16* __restrict__ w1h, f16* __restrict__ w1l,
    const float* __restrict__ enc_w2, f16* __restrict__ w2h, f16* __restrict__ w2l,
    const float* __restrict__ codebook, f16* __restrict__ cbh, f16* __restrict__ cbl,
    unsigned short* __restrict__ cb_bf,
    const float* __restrict__ dec_w1, unsigned short* __restrict__ w1Td,
    const float* __restrict__ dec_w2, unsigned short* __restrict__ w2Td,
    float* __restrict__ cnorm,
    const float* __restrict__ x, f16* __restrict__ xh, f16* __restrict__ xl)
{
    const int b = blockIdx.x;
    const int t = threadIdx.x;
    if (b < 3072) {                       // split^T enc_w1 [1024][768] -> [768][1024]
        const int i = b * 256 + t;
        const int n = i >> 10, k = i & 1023;
        f16 h, l; splitf(enc_w1[(size_t)k * 768 + n], h, l);
        w1h[i] = h; w1l[i] = l;
    } else if (b < 4608) {                // split^T enc_w2 [768][512] -> [512][768]
        const int i = (b - 3072) * 256 + t;
        const int n = i / 768, k = i - n * 768;
        f16 h, l; splitf(enc_w2[(size_t)k * 512 + n], h, l);
        w2h[i] = h; w2l[i] = l;
    } else if (b < 5632) {                // split codebook
        const int i = (b - 4608) * 256 + t;
        f16 h, l; splitf(codebook[i], h, l);
        cbh[i] = h; cbl[i] = l;
    } else if (b < 6656) {                // codebook -> bf16
        const int i = (b - 5632) * 256 + t;
        cb_bf[i] = f2bf(codebook[i]);
    } else if (b < 8192) {                // conv^T dec_w1 [512][768] -> [768][512]
        const int i = (b - 6656) * 256 + t;
        const int n = i >> 9, k = i & 511;
        w1Td[i] = f2bf(dec_w1[(size_t)k * 768 + n]);
    } else if (b < 11264) {               // conv^T dec_w2 [768][1024] -> [1024][768]
        const int i = (b - 8192) * 256 + t;
        const int n = i / 768, k = i - n * 768;
        w2Td[i] = f2bf(dec_w2[(size_t)k * 1024 + n]);
    } else if (b < 11392) {               // codebook row sum-squares
        const int lane = t & 63, wid = t >> 6;
        const size_t row = (size_t)(b - 11264) * 4 + wid;
        const float* p = codebook + row * 512;
        float s = 0.f;
#pragma unroll
        for (int e = 0; e < 8; ++e) { const float v = p[lane + e * 64]; s = fmaf(v, v, s); }
#pragma unroll
        for (int m = 1; m < 64; m <<= 1) s += __shfl_xor(s, m);
        if (lane == 0) cnorm[row] = s;
    } else {                              // split x (8 floats / thread)
        const size_t i = ((size_t)(b - 11392) * 256 + t);
        const float4 a4 = ((const float4*)x)[i * 2];
        const float4 b4 = ((const float4*)x)[i * 2 + 1];
        const float fv[8] = {a4.x, a4.y, a4.z, a4.w, b4.x, b4.y, b4.z, b4.w};
        f16 hv[8] __attribute__((aligned(16)));
        f16 lv[8] __attribute__((aligned(16)));
#pragma unroll
        for (int j = 0; j < 8; ++j) splitf(fv[j], hv[j], lv[j]);
        *(half8v*)(xh + i * 8) = *(half8v*)hv;
        *(half8v*)(xl + i * 8) = *(half8v*)lv;
    }
}

// ---------------------------------------------------------------------------
// LayerNorm + ReLU on f16 hi/lo pair (in place), fp32 math, vectorized loads.
// One wave per row, half8v chunks.
// ---------------------------------------------------------------------------
template<int H, bool ENORM>
__global__ __launch_bounds__(256) void ln_pair_k(
    f16* __restrict__ hi, f16* __restrict__ lo, const float* __restrict__ g,
    const float* __restrict__ b, float* __restrict__ enorm)
{
    constexpr int NCH = H / 8;               // chunks per row
    constexpr int MAXC = (NCH + 63) / 64;    // chunks per lane
    const int lane = threadIdx.x & 63;
    const int wid = threadIdx.x >> 6;
    const size_t row = (size_t)blockIdx.x * 4 + wid;
    f16* ph = hi + row * H;
    f16* pl = lo + row * H;

    float h[MAXC * 8];
    float s = 0.f;
#pragma unroll
    for (int e = 0; e < MAXC; ++e) {
        const int c = lane + e * 64;
        if ((NCH % 64 == 0) || c < NCH) {
            const half8v vh = *(const half8v*)(ph + c * 8);
            const half8v vl = *(const half8v*)(pl + c * 8);
#pragma unroll
            for (int j = 0; j < 8; ++j) {
                h[e * 8 + j] = (float)vh[j] + (float)vl[j] * (1.f / 2048.f);
                s += h[e * 8 + j];
            }
        }
    }
#pragma unroll
    for (int m = 1; m < 64; m <<= 1) s += __shfl_xor(s, m);
    const float mu = s * (1.f / H);

    float vs = 0.f;
#pragma unroll
    for (int e = 0; e < MAXC; ++e) {
        const int c = lane + e * 64;
        if ((NCH % 64 == 0) || c < NCH) {
#pragma unroll
            for (int j = 0; j < 8; ++j) {
                const float d = h[e * 8 + j] - mu;
                vs = fmaf(d, d, vs);
            }
        }
    }
#pragma unroll
    for (int m = 1; m < 64; m <<= 1) vs += __shfl_xor(vs, m);
    const float rstd = rsqrtf(vs * (1.f / H) + 1e-5f);

    float q = 0.f;
#pragma unroll
    for (int e = 0; e < MAXC; ++e) {
        const int c = lane + e * 64;
        if ((NCH % 64 == 0) || c < NCH) {
            f16 oh[8] __attribute__((aligned(16)));
            f16 ol[8] __attribute__((aligned(16)));
#pragma unroll
            for (int j = 0; j < 8; ++j) {
                float o = (h[e * 8 + j] - mu) * rstd * g[c * 8 + j] + b[c * 8 + j];
                o = fmaxf(o, 0.f);
                splitf(o, oh[j], ol[j]);
                q = fmaf(o, o, q);
            }
            *(half8v*)(ph + c * 8) = *(half8v*)oh;
            *(half8v*)(pl + c * 8) = *(half8v*)ol;
        }
    }
    if (ENORM) {
#pragma unroll
        for (int m = 1; m < 64; m <<= 1) q += __shfl_xor(q, m);
        if (lane == 0) enorm[row] = q;
    }
}

__global__ __launch_bounds__(256) void vq_reduce_k(
    const float* __restrict__ cand_v, const int* __restrict__ cand_i,
    const float* __restrict__ enorm, float* __restrict__ out_idx_f,
    int* __restrict__ out_idx, float* __restrict__ commit_sum, int ntiles)
{
    const int tid = threadIdx.x;
    const int m = blockIdx.x * 256 + tid;
    float bv = cand_v[(size_t)m * ntiles];
    int bi = cand_i[(size_t)m * ntiles];
    for (int t = 1; t < ntiles; ++t) {
        const float v = cand_v[(size_t)m * ntiles + t];
        const int i = cand_i[(size_t)m * ntiles + t];
        if (v < bv) { bv = v; bi = i; }
    }
    out_idx_f[m] = (float)bi;
    out_idx[m] = bi;
    const float d2 = enorm[m] + bv;

    __shared__ float red[256];
    red[tid] = d2;
    __syncthreads();
    for (int s = 128; s > 0; s >>= 1) {
        if (tid < s) red[tid] += red[tid + s];
        __syncthreads();
    }
    if (tid == 0) atomicAdd(commit_sum, red[0]);
}

__global__ __launch_bounds__(256) void pooled_k(const int* __restrict__ idx,
                                                const float* __restrict__ cb,
                                                float* __restrict__ pooled)
{
    const int b = blockIdx.x;
    const int d = threadIdx.x;
    float a0 = 0.f, a1 = 0.f;
    for (int t = 0; t < 512; ++t) {
        const int id = idx[b * 512 + t];
        a0 += cb[(size_t)id * 512 + d];
        a1 += cb[(size_t)id * 512 + d + 256];
    }
    pooled[b * 512 + d] = a0 * (1.f / 512.f);
    pooled[b * 512 + d + 256] = a1 * (1.f / 512.f);
}

__global__ __launch_bounds__(256) void proj_k(
    const float* __restrict__ pooled, const float* __restrict__ w1,
    const float* __restrict__ b1, const float* __restrict__ w2,
    const float* __restrict__ b2, float* __restrict__ nproj)
{
    __shared__ float sp[512];
    __shared__ float sh[256];
    __shared__ float red[128];
    const int b = blockIdx.x, tid = threadIdx.x;
    sp[tid] = pooled[b * 512 + tid];
    sp[tid + 256] = pooled[b * 512 + tid + 256];
    __syncthreads();

    float acc = b1[tid];
    for (int k = 0; k < 512; ++k) acc = fmaf(sp[k], w1[k * 256 + tid], acc);
    sh[tid] = fmaxf(acc, 0.f);
    __syncthreads();

    float p = 0.f;
    if (tid < 128) {
        p = b2[tid];
        for (int k = 0; k < 256; ++k) p = fmaf(sh[k], w2[k * 128 + tid], p);
        red[tid] = p * p;
    }
    __syncthreads();
    for (int s = 64; s > 0; s >>= 1) {
        if (tid < s) red[tid] += red[tid + s];
        __syncthreads();
    }
    if (tid < 128) {
        const float nrm = fmaxf(sqrtf(red[0]), 1e-12f);
        nproj[b * 128 + tid] = p / nrm;
    }
}

__global__ __launch_bounds__(256) void contrast_k(
    const float* __restrict__ nproj, const float* __restrict__ sums,
    float* __restrict__ out5)
{
    __shared__ float s_np[64 * 128];
    __shared__ float s_sim[64 * 64];
    __shared__ float s_row[64];
    const int tid = threadIdx.x;
    for (int i = tid; i < 64 * 128; i += 256) s_np[i] = nproj[i];
    __syncthreads();
    for (int p = tid; p < 64 * 64; p += 256) {
        const int i = p >> 6, j = p & 63;
        float d = 0.f;
        for (int k = 0; k < 128; ++k) d = fmaf(s_np[i * 128 + k], s_np[j * 128 + k], d);
        s_sim[p] = d * 10.f;
    }
    __syncthreads();
    if (tid < 64) {
        float mx = -1e30f;
        for (int j = 0; j < 64; ++j) mx = fmaxf(mx, s_sim[tid * 64 + j]);
        float se = 0.f;
        for (int j = 0; j < 64; ++j) se += expf(s_sim[tid * 64 + j] - mx);
        const float lse = mx + logf(se);
        s_row[tid] = s_sim[tid * 64 + tid] - lse;
    }
    __syncthreads();
    if (tid == 0) {
        float c = 0.f;
        for (int i = 0; i < 64; ++i) c += s_row[i];
        const float contr = -c / 64.f;
        const float recon = sums[0] / ((float)BT_TOK * (float)D_IN);
        const float commit = sums[1] / ((float)BT_TOK * (float)H2D);
        const float cbl = commit;
        const float total = recon * 1.0f + commit * 1.0f + cbl * 0.25f + contr * 0.5f;
        out5[0] = total;
        out5[1] = recon;
        out5[2] = commit;
        out5[3] = cbl;
        out5[4] = contr;
    }
}

__global__ void init_k(float* sums)
{
    if (threadIdx.x < 2) sums[threadIdx.x] = 0.f;
}

extern "C" void kernel_launch(void* const* d_in, const int* in_sizes, int n_in,
                              void* d_out, int out_size, void* d_ws, size_t ws_size,
                              hipStream_t stream)
{
    const float* x       = (const float*)d_in[0];
    const float* enc_w1  = (const float*)d_in[1];
    const float* enc_b1  = (const float*)d_in[2];
    const float* ln1_g   = (const float*)d_in[3];
    const float* ln1_b   = (const float*)d_in[4];
    const float* enc_w2  = (const float*)d_in[5];
    const float* enc_b2  = (const float*)d_in[6];
    const float* ln2_g   = (const float*)d_in[7];
    const float* ln2_b   = (const float*)d_in[8];
    const float* codebook= (const float*)d_in[9];
    const float* dec_w1  = (const float*)d_in[10];
    const float* dec_b1  = (const float*)d_in[11];
    const float* dec_w2  = (const float*)d_in[12];
    const float* dec_b2  = (const float*)d_in[13];
    const float* proj_w1 = (const float*)d_in[14];
    const float* proj_b1 = (const float*)d_in[15];
    const float* proj_w2 = (const float*)d_in[16];
    const float* proj_b2 = (const float*)d_in[17];
    float* out = (float*)d_out;

    char* wsb = (char*)d_ws;
    size_t off = 0;
    auto alloc = [&](size_t bytes) {
        void* p = wsb + off;
        off += (bytes + 255) & ~(size_t)255;
        return p;
    };

    f16* h1h  = (f16*)alloc((size_t)BT_TOK * H1D * 2);
    f16* h1l  = (f16*)alloc((size_t)BT_TOK * H1D * 2);
    f16* w1h  = (f16*)alloc((size_t)H1D * D_IN * 2);
    f16* w1l  = (f16*)alloc((size_t)H1D * D_IN * 2);
    f16* w2h  = (f16*)alloc((size_t)H2D * H1D * 2);
    f16* w2l  = (f16*)alloc((size_t)H2D * H1D * 2);
    f16* cbh  = (f16*)alloc((size_t)KCB * H2D * 2);
    f16* cbl  = (f16*)alloc((size_t)KCB * H2D * 2);
    unsigned short* cb_bf = (unsigned short*)alloc((size_t)KCB * H2D * 2);
    unsigned short* w1Td  = (unsigned short*)alloc((size_t)H1D * H2D * 2);
    unsigned short* w2Td  = (unsigned short*)alloc((size_t)D_IN * H1D * 2);
    float* cnorm  = (float*)alloc(KCB * 4);
    float* enorm  = (float*)alloc(BT_TOK * 4);
    float* cand_v = (float*)alloc((size_t)BT_TOK * 8 * 4);
    int*   cand_i = (int*)alloc((size_t)BT_TOK * 8 * 4);
    int*   idxbuf = (int*)alloc(BT_TOK * 4);
    float* pooled = (float*)alloc(64 * 512 * 4);
    float* nproj  = (float*)alloc(64 * 128 * 4);
    float* sums   = (float*)alloc(2 * 4);
    unsigned short* dh_bf = (unsigned short*)h1h;  // h1 pair dead after GEMM2

    // Pre-split x path needs 2 x 64 MiB more; enc pair aliases into xh
    // (xh dead after GEMM1, enc written by GEMM2).
    const size_t xbytes = (size_t)BT_TOK * D_IN * 2;
    const bool presplit = (off + 2 * (xbytes + 256)) <= ws_size;
    f16 *xh = nullptr, *xl = nullptr, *ench, *encl;
    if (presplit) {
        xh = (f16*)alloc(xbytes);
        xl = (f16*)alloc(xbytes);
        ench = xh;                               // 33.5 MB
        encl = xh + (size_t)BT_TOK * H2D;        // next 33.5 MB (fits in 67)
    } else {
        ench = (f16*)alloc((size_t)BT_TOK * H2D * 2);
        encl = (f16*)alloc((size_t)BT_TOK * H2D * 2);
    }

    const dim3 blk(256);

    hipLaunchKernelGGL(init_k, dim3(1), blk, 0, stream, sums);

    // fused prep (weights, codebook, cnorm, optional x split)
    prep_k<<<dim3(presplit ? 27776 : 11392), blk, 0, stream>>>(
        enc_w1, w1h, w1l, enc_w2, w2h, w2l, codebook, cbh, cbl, cb_bf,
        dec_w1, w1Td, dec_w2, w2Td, cnorm, x, xh, xl);

    // encoder layer 1: h1 = x @ enc_w1 + b1
    if (presplit) {
        sgemm_k<0><<<dim3(H1D / 128, BT_TOK / 128), blk, 0, stream>>>(
            xh, xl, w1h, w1l, enc_b1, h1h, h1l, nullptr, nullptr, nullptr, H1D, D_IN);
    } else {
        sgemm_x_k<<<dim3(H1D / 128, BT_TOK / 128), blk, 0, stream>>>(
            x, w1h, w1l, enc_b1, h1h, h1l, H1D, D_IN);
    }
    ln_pair_k<H1D, false><<<dim3(BT_TOK / 4), blk, 0, stream>>>(h1h, h1l, ln1_g, ln1_b, nullptr);

    // encoder layer 2: enc = h1 @ enc_w2 + b2
    sgemm_k<0><<<dim3(H2D / 128, BT_TOK / 128), blk, 0, stream>>>(
        h1h, h1l, w2h, w2l, enc_b2, ench, encl, nullptr, nullptr, nullptr, H2D, H1D);
    ln_pair_k<H2D, true><<<dim3(BT_TOK / 4), blk, 0, stream>>>(ench, encl, ln2_g, ln2_b, enorm);

    // VQ scores + tile argmin (exact fp32-equivalent via split)
    sgemm_k<1><<<dim3(KCB / 128, BT_TOK / 128), blk, 0, stream>>>(
        ench, encl, cbh, cbl, nullptr, nullptr, nullptr, cnorm, cand_v, cand_i, KCB, H2D);
    vq_reduce_k<<<dim3(BT_TOK / 256), blk, 0, stream>>>(
        cand_v, cand_i, enorm, out, idxbuf, sums + 1, 8);

    pooled_k<<<dim3(64), blk, 0, stream>>>(idxbuf, codebook, pooled);

    // decoder (bf16 MFMA)
    mfma_gemm_k<0><<<dim3(H1D / 128, BT_TOK / 128), blk, 0, stream>>>(
        cb_bf, w1Td, dec_b1, dh_bf, nullptr, nullptr, idxbuf, H1D, H2D);
    mfma_gemm_k<1><<<dim3(D_IN / 128, BT_TOK / 128), blk, 0, stream>>>(
        dh_bf, w2Td, dec_b2, nullptr, x, sums, nullptr, D_IN, H1D);

    proj_k<<<dim3(64), blk, 0, stream>>>(pooled, proj_w1, proj_b1, proj_w2, proj_b2, nproj);
    contrast_k<<<dim3(1), blk, 0, stream>>>(nproj, sums, out + BT_TOK);
}

// Round 6
// 908.764 us; speedup vs baseline: 1.0014x; 1.0014x over previous
//
#include <hip/hip_runtime.h>
#include <math.h>

#define BT_TOK 32768
#define D_IN   1024
#define H1D    768
#define H2D    512
#define KCB    512

typedef short bf16x8 __attribute__((ext_vector_type(8)));
typedef _Float16 f16;
typedef _Float16 half8v __attribute__((ext_vector_type(8)));
typedef float f32x16 __attribute__((ext_vector_type(16)));

#define GLDS16(g, l) \
    __builtin_amdgcn_global_load_lds((const __attribute__((address_space(1))) void*)(g), \
                                     (__attribute__((address_space(3))) void*)(l), 16, 0, 0)

__device__ __forceinline__ unsigned short f2bf(float f) {
    union { float f; unsigned u; } v; v.f = f;
    const unsigned r = v.u + 0x7FFFu + ((v.u >> 16) & 1u);
    return (unsigned short)(r >> 16);
}

// split convention: hi = f16(v), lo = f16((v-hi)*2048); v ~= hi + lo/2048
__device__ __forceinline__ void splitf(float v, f16& h, f16& l) {
    h = (f16)v;
    l = (f16)((v - (float)h) * 2048.f);
}

// LDS tile layout (per operand): [kk 0..1][j2 0..1][64 rows][32 f16 = 64 B]
// with XOR chunk swizzle: logical 16-B chunk c of row r lives at chunk c^(r&3).
// GLDS destination is lane-fixed (base + lane*16), so the swizzle is applied
// to the SOURCE column each lane fetches.

// ---------------------------------------------------------------------------
// Split-FP16 MFMA GEMM, 32x32x16, BK=64. 128x128 block, 2x2 waves, each wave
// 2x2 tiles of 32x32; 3 MFMAs per frag pair (hh, hl, lh).
// ASPLIT: A is fp32 [M][Kd], split in-kernel to LDS (GEMM1).
// EPI 0: +bias, write f16 hi/lo pair. EPI 1: VQ tile-argmin.
// ---------------------------------------------------------------------------
template<int EPI, bool ASPLIT>
__global__ __launch_bounds__(256, 2) void sgemm_k(
    const float* __restrict__ Af,
    const f16* __restrict__ Ah, const f16* __restrict__ Al,
    const f16* __restrict__ Bh, const f16* __restrict__ Bl,
    const float* __restrict__ bias,
    f16* __restrict__ Ch, f16* __restrict__ Cl,
    const float* __restrict__ cnorm,
    float* __restrict__ cand_v, int* __restrict__ cand_i,
    int N, int Kd)
{
    __shared__ __align__(16) f16 sAh[2 * 128 * 32];
    __shared__ __align__(16) f16 sAl[2 * 128 * 32];
    __shared__ __align__(16) f16 sBh[2 * 128 * 32];
    __shared__ __align__(16) f16 sBl[2 * 128 * 32];

    const int t = threadIdx.x;
    const int lane = t & 63, wave = t >> 6;
    const int wm = wave & 1, wn = wave >> 1;
    const int row0 = blockIdx.y * 128, col0 = blockIdx.x * 128;

    f32x16 acc_h[2][2], acc_l[2][2];
#pragma unroll
    for (int i = 0; i < 2; ++i)
#pragma unroll
        for (int j = 0; j < 2; ++j) {
#pragma unroll
            for (int r = 0; r < 16; ++r) { acc_h[i][j][r] = 0.f; acc_l[i][j][r] = 0.f; }
        }

    // GLDS staging coords: lane -> row wave*16+(lane>>2), swizzled source chunk
    const int srow = wave * 16 + (lane >> 2);
    const int scol = (((lane & 3) ^ ((lane >> 2) & 3)) * 8);   // f16 units

    const f16* gBh = Bh + (size_t)(col0 + srow) * Kd + scol;
    const f16* gBl = Bl + (size_t)(col0 + srow) * Kd + scol;
    const f16* gAh = nullptr; const f16* gAl = nullptr;
    const float* gx = nullptr;
    int xr = 0, xkk = 0, xrb = 0;
    if (ASPLIT) {
        xr = t >> 1; xkk = t & 1;
        gx = Af + (size_t)(row0 + xr) * Kd + xkk * 32;
        xrb = xkk * 8192 + (xr >> 6) * 4096 + (xr & 63) * 64;
    } else {
        gAh = Ah + (size_t)(row0 + srow) * Kd + scol;
        gAl = Al + (size_t)(row0 + srow) * Kd + scol;
    }

    const int fr32 = lane & 31;
    const int xhi = lane >> 5;          // chunk sub-select

    for (int k0 = 0; k0 < Kd; k0 += 64) {
        if (ASPLIT) {
            const float4* gp = (const float4*)(gx + k0);
#pragma unroll
            for (int c = 0; c < 4; ++c) {
                const float4 f0 = gp[c * 2];
                const float4 f1 = gp[c * 2 + 1];
                const float fv[8] = {f0.x, f0.y, f0.z, f0.w, f1.x, f1.y, f1.z, f1.w};
                f16 hv[8] __attribute__((aligned(16)));
                f16 lv[8] __attribute__((aligned(16)));
#pragma unroll
                for (int i = 0; i < 8; ++i) splitf(fv[i], hv[i], lv[i]);
                const int dst = xrb + ((c ^ (xr & 3)) << 4);
                *(half8v*)((char*)sAh + dst) = *(half8v*)hv;
                *(half8v*)((char*)sAl + dst) = *(half8v*)lv;
            }
        }
#pragma unroll
        for (int kk = 0; kk < 2; ++kk)
#pragma unroll
            for (int j2 = 0; j2 < 2; ++j2) {
                const size_t go = (size_t)j2 * 64 * Kd + kk * 32 + k0;
                const int lo = kk * 8192 + j2 * 4096 + wave * 1024;
                if (!ASPLIT) {
                    GLDS16(gAh + go, (char*)sAh + lo);
                    GLDS16(gAl + go, (char*)sAl + lo);
                }
                GLDS16(gBh + go, (char*)sBh + lo);
                GLDS16(gBl + go, (char*)sBl + lo);
            }
        __syncthreads();

#pragma unroll
        for (int ks = 0; ks < 4; ++ks) {
            const int kk = ks >> 1;
            const int X = (ks & 1) * 2 + xhi;   // logical 16-B chunk
            half8v fah[2], fal[2];
#pragma unroll
            for (int mi = 0; mi < 2; ++mi) {
                const int rw = mi * 32 + fr32;
                const int ao = kk * 8192 + wm * 4096 + rw * 64 + ((X ^ (rw & 3)) << 4);
                fah[mi] = *(const half8v*)((char*)sAh + ao);
                fal[mi] = *(const half8v*)((char*)sAl + ao);
            }
#pragma unroll
            for (int ni = 0; ni < 2; ++ni) {
                const int rw = ni * 32 + fr32;
                const int bo = kk * 8192 + wn * 4096 + rw * 64 + ((X ^ (rw & 3)) << 4);
                const half8v fbh = *(const half8v*)((char*)sBh + bo);
                const half8v fbl = *(const half8v*)((char*)sBl + bo);
#pragma unroll
                for (int mi = 0; mi < 2; ++mi) {
                    acc_h[mi][ni] = __builtin_amdgcn_mfma_f32_32x32x16_f16(
                        fah[mi], fbh, acc_h[mi][ni], 0, 0, 0);
                    acc_l[mi][ni] = __builtin_amdgcn_mfma_f32_32x32x16_f16(
                        fah[mi], fbl, acc_l[mi][ni], 0, 0, 0);
                    acc_l[mi][ni] = __builtin_amdgcn_mfma_f32_32x32x16_f16(
                        fal[mi], fbh, acc_l[mi][ni], 0, 0, 0);
                }
            }
        }
        __syncthreads();
    }

    // 32x32 C/D: col = lane&31, row = (reg&3) + 8*(reg>>2) + 4*(lane>>5)
    const int cC = lane & 31;
    const int rB = 4 * (lane >> 5);

    if (EPI == 0) {
#pragma unroll
        for (int ni = 0; ni < 2; ++ni) {
            const int col = col0 + wn * 64 + ni * 32 + cC;
            const float bb = bias[col];
#pragma unroll
            for (int mi = 0; mi < 2; ++mi)
#pragma unroll
                for (int rg = 0; rg < 16; ++rg) {
                    const size_t row = row0 + wm * 64 + mi * 32
                                     + (rg & 3) + 8 * (rg >> 2) + rB;
                    const float v = acc_h[mi][ni][rg] + acc_l[mi][ni][rg] * (1.f / 2048.f) + bb;
                    f16 vh, vl;
                    splitf(v, vh, vl);
                    Ch[row * N + col] = vh;
                    Cl[row * N + col] = vl;
                }
        }
    } else {
#pragma unroll
        for (int mi = 0; mi < 2; ++mi)
#pragma unroll
            for (int rg = 0; rg < 16; ++rg) {
                float bestv = 1e30f;
                int besti = 0;
#pragma unroll
                for (int ni = 0; ni < 2; ++ni) {
                    const int col = col0 + wn * 64 + ni * 32 + cC;
                    const float v = cnorm[col]
                        - 2.f * (acc_h[mi][ni][rg] + acc_l[mi][ni][rg] * (1.f / 2048.f));
                    if (v < bestv || (v == bestv && col < besti)) { bestv = v; besti = col; }
                }
#pragma unroll
                for (int m = 1; m < 32; m <<= 1) {   // reduce within 32-lane half
                    const float ov = __shfl_xor(bestv, m);
                    const int oi = __shfl_xor(besti, m);
                    if (ov < bestv || (ov == bestv && oi < besti)) { bestv = ov; besti = oi; }
                }
                if (cC == 0) {
                    const size_t row = row0 + wm * 64 + mi * 32
                                     + (rg & 3) + 8 * (rg >> 2) + rB;
                    cand_v[row * 8 + blockIdx.x * 2 + wn] = bestv;
                    cand_i[row * 8 + blockIdx.x * 2 + wn] = besti;
                }
            }
    }
}

// ---------------------------------------------------------------------------
// bf16 MFMA GEMM for the decoder (loss path; 2% tolerance). 32x32x16, BK=64,
// same swizzled staging geometry.
// ---------------------------------------------------------------------------
template<int EPI>
__global__ __launch_bounds__(256, 2) void mfma_gemm_k(
    const unsigned short* __restrict__ A, const unsigned short* __restrict__ BT,
    const float* __restrict__ bias, unsigned short* __restrict__ Cbf,
    const float* __restrict__ Xref, float* __restrict__ lsum_out,
    const int* __restrict__ gidx, int N, int Kd)
{
    __shared__ __align__(16) unsigned short sA[2 * 128 * 32];
    __shared__ __align__(16) unsigned short sB[2 * 128 * 32];

    const int t = threadIdx.x;
    const int lane = t & 63, wave = t >> 6;
    const int wm = wave & 1, wn = wave >> 1;
    const int row0 = blockIdx.y * 128, col0 = blockIdx.x * 128;

    f32x16 acc[2][2];
#pragma unroll
    for (int i = 0; i < 2; ++i)
#pragma unroll
        for (int j = 0; j < 2; ++j)
#pragma unroll
            for (int r = 0; r < 16; ++r) acc[i][j][r] = 0.f;

    const int srow = wave * 16 + (lane >> 2);
    const int scol = (((lane & 3) ^ ((lane >> 2) & 3)) * 8);

    int ar[2];
    ar[0] = row0 + srow; ar[1] = row0 + 64 + srow;
    if (gidx) { ar[0] = gidx[row0 + srow]; ar[1] = gidx[row0 + 64 + srow]; }

    const int fr32 = lane & 31;
    const int xhi = lane >> 5;

    for (int k0 = 0; k0 < Kd; k0 += 64) {
#pragma unroll
        for (int kk = 0; kk < 2; ++kk)
#pragma unroll
            for (int j2 = 0; j2 < 2; ++j2) {
                const int lo = kk * 8192 + j2 * 4096 + wave * 1024;
                GLDS16(A + (size_t)ar[j2] * Kd + kk * 32 + scol + k0, (char*)sA + lo);
                GLDS16(BT + (size_t)(col0 + j2 * 64 + srow) * Kd + kk * 32 + scol + k0,
                       (char*)sB + lo);
            }
        __syncthreads();

#pragma unroll
        for (int ks = 0; ks < 4; ++ks) {
            const int kk = ks >> 1;
            const int X = (ks & 1) * 2 + xhi;
            bf16x8 a[2];
#pragma unroll
            for (int mi = 0; mi < 2; ++mi) {
                const int rw = mi * 32 + fr32;
                a[mi] = *(const bf16x8*)((char*)sA + kk * 8192 + wm * 4096
                                         + rw * 64 + ((X ^ (rw & 3)) << 4));
            }
#pragma unroll
            for (int ni = 0; ni < 2; ++ni) {
                const int rw = ni * 32 + fr32;
                const bf16x8 b = *(const bf16x8*)((char*)sB + kk * 8192 + wn * 4096
                                                  + rw * 64 + ((X ^ (rw & 3)) << 4));
#pragma unroll
                for (int mi = 0; mi < 2; ++mi)
                    acc[mi][ni] = __builtin_amdgcn_mfma_f32_32x32x16_bf16(
                        a[mi], b, acc[mi][ni], 0, 0, 0);
            }
        }
        __syncthreads();
    }

    const int cC = lane & 31;
    const int rB = 4 * (lane >> 5);

    if (EPI == 0) {
#pragma unroll
        for (int ni = 0; ni < 2; ++ni) {
            const int col = col0 + wn * 64 + ni * 32 + cC;
            const float bb = bias[col];
#pragma unroll
            for (int mi = 0; mi < 2; ++mi)
#pragma unroll
                for (int rg = 0; rg < 16; ++rg) {
                    const size_t row = row0 + wm * 64 + mi * 32
                                     + (rg & 3) + 8 * (rg >> 2) + rB;
                    const float v = fmaxf(acc[mi][ni][rg] + bb, 0.f);
                    Cbf[row * N + col] = f2bf(v);
                }
        }
    } else {
        float ls = 0.f;
#pragma unroll
        for (int ni = 0; ni < 2; ++ni) {
            const int col = col0 + wn * 64 + ni * 32 + cC;
            const float bb = bias[col];
#pragma unroll
            for (int mi = 0; mi < 2; ++mi)
#pragma unroll
                for (int rg = 0; rg < 16; ++rg) {
                    const size_t row = row0 + wm * 64 + mi * 32
                                     + (rg & 3) + 8 * (rg >> 2) + rB;
                    const float d = acc[mi][ni][rg] + bb - Xref[row * N + col];
                    ls = fmaf(d, d, ls);
                }
        }
        __shared__ float red[256];
        red[t] = ls;
        __syncthreads();
        for (int s = 128; s > 0; s >>= 1) {
            if (t < s) red[t] += red[t + s];
            __syncthreads();
        }
        if (t == 0) atomicAdd(lsum_out, red[0]);
    }
}

// ---------------------------------------------------------------------------
// Fused prep: weight splits/transposes/conversions + codebook norms.
// ---------------------------------------------------------------------------
__global__ __launch_bounds__(256) void prep_k(
    const float* __restrict__ enc_w1, f16* __restrict__ w1h, f16* __restrict__ w1l,
    const float* __restrict__ enc_w2, f16* __restrict__ w2h, f16* __restrict__ w2l,
    const float* __restrict__ codebook, f16* __restrict__ cbh, f16* __restrict__ cbl,
    unsigned short* __restrict__ cb_bf,
    const float* __restrict__ dec_w1, unsigned short* __restrict__ w1Td,
    const float* __restrict__ dec_w2, unsigned short* __restrict__ w2Td,
    float* __restrict__ cnorm)
{
    const int b = blockIdx.x;
    const int t = threadIdx.x;
    if (b < 3072) {                       // split^T enc_w1 [1024][768] -> [768][1024]
        const int i = b * 256 + t;
        const int n = i >> 10, k = i & 1023;
        f16 h, l; splitf(enc_w1[(size_t)k * 768 + n], h, l);
        w1h[i] = h; w1l[i] = l;
    } else if (b < 4608) {                // split^T enc_w2 [768][512] -> [512][768]
        const int i = (b - 3072) * 256 + t;
        const int n = i / 768, k = i - n * 768;
        f16 h, l; splitf(enc_w2[(size_t)k * 512 + n], h, l);
        w2h[i] = h; w2l[i] = l;
    } else if (b < 5632) {                // split codebook
        const int i = (b - 4608) * 256 + t;
        f16 h, l; splitf(codebook[i], h, l);
        cbh[i] = h; cbl[i] = l;
    } else if (b < 6656) {                // codebook -> bf16
        const int i = (b - 5632) * 256 + t;
        cb_bf[i] = f2bf(codebook[i]);
    } else if (b < 8192) {                // conv^T dec_w1 [512][768] -> [768][512]
        const int i = (b - 6656) * 256 + t;
        const int n = i >> 9, k = i & 511;
        w1Td[i] = f2bf(dec_w1[(size_t)k * 768 + n]);
    } else if (b < 11264) {               // conv^T dec_w2 [768][1024] -> [1024][768]
        const int i = (b - 8192) * 256 + t;
        const int n = i / 768, k = i - n * 768;
        w2Td[i] = f2bf(dec_w2[(size_t)k * 1024 + n]);
    } else {                              // codebook row sum-squares
        const int lane = t & 63, wid = t >> 6;
        const size_t row = (size_t)(b - 11264) * 4 + wid;
        const float* p = codebook + row * 512;
        float s = 0.f;
#pragma unroll
        for (int e = 0; e < 8; ++e) { const float v = p[lane + e * 64]; s = fmaf(v, v, s); }
#pragma unroll
        for (int m = 1; m < 64; m <<= 1) s += __shfl_xor(s, m);
        if (lane == 0) cnorm[row] = s;
    }
}

// ---------------------------------------------------------------------------
// LayerNorm + ReLU on f16 hi/lo pair (in place), fp32 math, vectorized.
// ---------------------------------------------------------------------------
template<int H, bool ENORM>
__global__ __launch_bounds__(256) void ln_pair_k(
    f16* __restrict__ hi, f16* __restrict__ lo, const float* __restrict__ g,
    const float* __restrict__ b, float* __restrict__ enorm)
{
    constexpr int NCH = H / 8;
    constexpr int MAXC = (NCH + 63) / 64;
    const int lane = threadIdx.x & 63;
    const int wid = threadIdx.x >> 6;
    const size_t row = (size_t)blockIdx.x * 4 + wid;
    f16* ph = hi + row * H;
    f16* pl = lo + row * H;

    float h[MAXC * 8];
    float s = 0.f;
#pragma unroll
    for (int e = 0; e < MAXC; ++e) {
        const int c = lane + e * 64;
        if ((NCH % 64 == 0) || c < NCH) {
            const half8v vh = *(const half8v*)(ph + c * 8);
            const half8v vl = *(const half8v*)(pl + c * 8);
#pragma unroll
            for (int j = 0; j < 8; ++j) {
                h[e * 8 + j] = (float)vh[j] + (float)vl[j] * (1.f / 2048.f);
                s += h[e * 8 + j];
            }
        }
    }
#pragma unroll
    for (int m = 1; m < 64; m <<= 1) s += __shfl_xor(s, m);
    const float mu = s * (1.f / H);

    float vs = 0.f;
#pragma unroll
    for (int e = 0; e < MAXC; ++e) {
        const int c = lane + e * 64;
        if ((NCH % 64 == 0) || c < NCH) {
#pragma unroll
            for (int j = 0; j < 8; ++j) {
                const float d = h[e * 8 + j] - mu;
                vs = fmaf(d, d, vs);
            }
        }
    }
#pragma unroll
    for (int m = 1; m < 64; m <<= 1) vs += __shfl_xor(vs, m);
    const float rstd = rsqrtf(vs * (1.f / H) + 1e-5f);

    float q = 0.f;
#pragma unroll
    for (int e = 0; e < MAXC; ++e) {
        const int c = lane + e * 64;
        if ((NCH % 64 == 0) || c < NCH) {
            f16 oh[8] __attribute__((aligned(16)));
            f16 ol[8] __attribute__((aligned(16)));
#pragma unroll
            for (int j = 0; j < 8; ++j) {
                float o = (h[e * 8 + j] - mu) * rstd * g[c * 8 + j] + b[c * 8 + j];
                o = fmaxf(o, 0.f);
                splitf(o, oh[j], ol[j]);
                q = fmaf(o, o, q);
            }
            *(half8v*)(ph + c * 8) = *(half8v*)oh;
            *(half8v*)(pl + c * 8) = *(half8v*)ol;
        }
    }
    if (ENORM) {
#pragma unroll
        for (int m = 1; m < 64; m <<= 1) q += __shfl_xor(q, m);
        if (lane == 0) enorm[row] = q;
    }
}

__global__ __launch_bounds__(256) void vq_reduce_k(
    const float* __restrict__ cand_v, const int* __restrict__ cand_i,
    const float* __restrict__ enorm, float* __restrict__ out_idx_f,
    int* __restrict__ out_idx, float* __restrict__ commit_sum, int ntiles)
{
    const int tid = threadIdx.x;
    const int m = blockIdx.x * 256 + tid;
    float bv = cand_v[(size_t)m * ntiles];
    int bi = cand_i[(size_t)m * ntiles];
    for (int t = 1; t < ntiles; ++t) {
        const float v = cand_v[(size_t)m * ntiles + t];
        const int i = cand_i[(size_t)m * ntiles + t];
        if (v < bv || (v == bv && i < bi)) { bv = v; bi = i; }
    }
    out_idx_f[m] = (float)bi;
    out_idx[m] = bi;
    const float d2 = enorm[m] + bv;

    __shared__ float red[256];
    red[tid] = d2;
    __syncthreads();
    for (int s = 128; s > 0; s >>= 1) {
        if (tid < s) red[tid] += red[tid + s];
        __syncthreads();
    }
    if (tid == 0) atomicAdd(commit_sum, red[0]);
}

__global__ __launch_bounds__(256) void pooled_k(const int* __restrict__ idx,
                                                const float* __restrict__ cb,
                                                float* __restrict__ pooled)
{
    const int b = blockIdx.x;
    const int d = threadIdx.x;
    float a0 = 0.f, a1 = 0.f;
    for (int t = 0; t < 512; ++t) {
        const int id = idx[b * 512 + t];
        a0 += cb[(size_t)id * 512 + d];
        a1 += cb[(size_t)id * 512 + d + 256];
    }
    pooled[b * 512 + d] = a0 * (1.f / 512.f);
    pooled[b * 512 + d + 256] = a1 * (1.f / 512.f);
}

__global__ __launch_bounds__(256) void proj_k(
    const float* __restrict__ pooled, const float* __restrict__ w1,
    const float* __restrict__ b1, const float* __restrict__ w2,
    const float* __restrict__ b2, float* __restrict__ nproj)
{
    __shared__ float sp[512];
    __shared__ float sh[256];
    __shared__ float red[128];
    const int b = blockIdx.x, tid = threadIdx.x;
    sp[tid] = pooled[b * 512 + tid];
    sp[tid + 256] = pooled[b * 512 + tid + 256];
    __syncthreads();

    float acc = b1[tid];
    for (int k = 0; k < 512; ++k) acc = fmaf(sp[k], w1[k * 256 + tid], acc);
    sh[tid] = fmaxf(acc, 0.f);
    __syncthreads();

    float p = 0.f;
    if (tid < 128) {
        p = b2[tid];
        for (int k = 0; k < 256; ++k) p = fmaf(sh[k], w2[k * 128 + tid], p);
        red[tid] = p * p;
    }
    __syncthreads();
    for (int s = 64; s > 0; s >>= 1) {
        if (tid < s) red[tid] += red[tid + s];
        __syncthreads();
    }
    if (tid < 128) {
        const float nrm = fmaxf(sqrtf(red[0]), 1e-12f);
        nproj[b * 128 + tid] = p / nrm;
    }
}

// one block per row i of the 64x64 sim matrix; writes log-softmax diag term
__global__ __launch_bounds__(256) void sim_k(
    const float* __restrict__ nproj, float* __restrict__ rowterm)
{
    __shared__ float ri[128];
    __shared__ float srow[64];
    const int i = blockIdx.x, t = threadIdx.x;
    if (t < 128) ri[t] = nproj[i * 128 + t];
    __syncthreads();

    const int j = t >> 2, q = t & 3;
    float d = 0.f;
    for (int k = q * 32; k < q * 32 + 32; ++k)
        d = fmaf(ri[k], nproj[j * 128 + k], d);
    d += __shfl_xor(d, 1);
    d += __shfl_xor(d, 2);
    if (q == 0) srow[j] = d * 10.f;   // / TEMP
    __syncthreads();

    if (t < 64) {
        float v = srow[t];
        float mx = v;
#pragma unroll
        for (int m = 1; m < 64; m <<= 1) mx = fmaxf(mx, __shfl_xor(mx, m));
        float e = expf(v - mx);
#pragma unroll
        for (int m = 1; m < 64; m <<= 1) e += __shfl_xor(e, m);
        if (t == 0) rowterm[i] = srow[i] - (mx + logf(e));
    }
}

__global__ __launch_bounds__(64) void final_k(
    const float* __restrict__ rowterm, const float* __restrict__ sums,
    float* __restrict__ out5)
{
    const int t = threadIdx.x;
    float c = rowterm[t];
#pragma unroll
    for (int m = 1; m < 64; m <<= 1) c += __shfl_xor(c, m);
    if (t == 0) {
        const float contr = -c / 64.f;
        const float recon = sums[0] / ((float)BT_TOK * (float)D_IN);
        const float commit = sums[1] / ((float)BT_TOK * (float)H2D);
        const float cbl = commit;
        const float total = recon * 1.0f + commit * 1.0f + cbl * 0.25f + contr * 0.5f;
        out5[0] = total;
        out5[1] = recon;
        out5[2] = commit;
        out5[3] = cbl;
        out5[4] = contr;
    }
}

__global__ void init_k(float* sums)
{
    if (threadIdx.x < 2) sums[threadIdx.x] = 0.f;
}

extern "C" void kernel_launch(void* const* d_in, const int* in_sizes, int n_in,
                              void* d_out, int out_size, void* d_ws, size_t ws_size,
                              hipStream_t stream)
{
    const float* x       = (const float*)d_in[0];
    const float* enc_w1  = (const float*)d_in[1];
    const float* enc_b1  = (const float*)d_in[2];
    const float* ln1_g   = (const float*)d_in[3];
    const float* ln1_b   = (const float*)d_in[4];
    const float* enc_w2  = (const float*)d_in[5];
    const float* enc_b2  = (const float*)d_in[6];
    const float* ln2_g   = (const float*)d_in[7];
    const float* ln2_b   = (const float*)d_in[8];
    const float* codebook= (const float*)d_in[9];
    const float* dec_w1  = (const float*)d_in[10];
    const float* dec_b1  = (const float*)d_in[11];
    const float* dec_w2  = (const float*)d_in[12];
    const float* dec_b2  = (const float*)d_in[13];
    const float* proj_w1 = (const float*)d_in[14];
    const float* proj_b1 = (const float*)d_in[15];
    const float* proj_w2 = (const float*)d_in[16];
    const float* proj_b2 = (const float*)d_in[17];
    float* out = (float*)d_out;

    char* wsb = (char*)d_ws;
    size_t off = 0;
    auto alloc = [&](size_t bytes) {
        void* p = wsb + off;
        off += (bytes + 255) & ~(size_t)255;
        return p;
    };

    f16* h1h  = (f16*)alloc((size_t)BT_TOK * H1D * 2);
    f16* h1l  = (f16*)alloc((size_t)BT_TOK * H1D * 2);
    f16* ench = (f16*)alloc((size_t)BT_TOK * H2D * 2);
    f16* encl = (f16*)alloc((size_t)BT_TOK * H2D * 2);
    f16* w1h  = (f16*)alloc((size_t)H1D * D_IN * 2);
    f16* w1l  = (f16*)alloc((size_t)H1D * D_IN * 2);
    f16* w2h  = (f16*)alloc((size_t)H2D * H1D * 2);
    f16* w2l  = (f16*)alloc((size_t)H2D * H1D * 2);
    f16* cbh  = (f16*)alloc((size_t)KCB * H2D * 2);
    f16* cbl  = (f16*)alloc((size_t)KCB * H2D * 2);
    unsigned short* cb_bf = (unsigned short*)alloc((size_t)KCB * H2D * 2);
    unsigned short* w1Td  = (unsigned short*)alloc((size_t)H1D * H2D * 2);
    unsigned short* w2Td  = (unsigned short*)alloc((size_t)D_IN * H1D * 2);
    float* cnorm  = (float*)alloc(KCB * 4);
    float* enorm  = (float*)alloc(BT_TOK * 4);
    float* cand_v = (float*)alloc((size_t)BT_TOK * 8 * 4);
    int*   cand_i = (int*)alloc((size_t)BT_TOK * 8 * 4);
    int*   idxbuf = (int*)alloc(BT_TOK * 4);
    float* pooled = (float*)alloc(64 * 512 * 4);
    float* nproj  = (float*)alloc(64 * 128 * 4);
    float* rowterm= (float*)alloc(64 * 4);
    float* sums   = (float*)alloc(2 * 4);
    unsigned short* dh_bf = (unsigned short*)h1h;  // h1 pair dead after GEMM2

    const dim3 blk(256);

    hipLaunchKernelGGL(init_k, dim3(1), blk, 0, stream, sums);

    prep_k<<<dim3(11392), blk, 0, stream>>>(
        enc_w1, w1h, w1l, enc_w2, w2h, w2l, codebook, cbh, cbl, cb_bf,
        dec_w1, w1Td, dec_w2, w2Td, cnorm);

    // encoder layer 1 (in-kernel x split): h1 = x @ enc_w1 + b1
    sgemm_k<0, true><<<dim3(H1D / 128, BT_TOK / 128), blk, 0, stream>>>(
        x, nullptr, nullptr, w1h, w1l, enc_b1, h1h, h1l, nullptr, nullptr, nullptr,
        H1D, D_IN);
    ln_pair_k<H1D, false><<<dim3(BT_TOK / 4), blk, 0, stream>>>(h1h, h1l, ln1_g, ln1_b, nullptr);

    // encoder layer 2: enc = h1 @ enc_w2 + b2
    sgemm_k<0, false><<<dim3(H2D / 128, BT_TOK / 128), blk, 0, stream>>>(
        nullptr, h1h, h1l, w2h, w2l, enc_b2, ench, encl, nullptr, nullptr, nullptr,
        H2D, H1D);
    ln_pair_k<H2D, true><<<dim3(BT_TOK / 4), blk, 0, stream>>>(ench, encl, ln2_g, ln2_b, enorm);

    // VQ scores + tile argmin (fp32-equivalent via split)
    sgemm_k<1, false><<<dim3(KCB / 128, BT_TOK / 128), blk, 0, stream>>>(
        nullptr, ench, encl, cbh, cbl, nullptr, nullptr, nullptr, cnorm, cand_v, cand_i,
        KCB, H2D);
    vq_reduce_k<<<dim3(BT_TOK / 256), blk, 0, stream>>>(
        cand_v, cand_i, enorm, out, idxbuf, sums + 1, 8);

    pooled_k<<<dim3(64), blk, 0, stream>>>(idxbuf, codebook, pooled);

    // decoder (bf16 MFMA)
    mfma_gemm_k<0><<<dim3(H1D / 128, BT_TOK / 128), blk, 0, stream>>>(
        cb_bf, w1Td, dec_b1, dh_bf, nullptr, nullptr, idxbuf, H1D, H2D);
    mfma_gemm_k<1><<<dim3(D_IN / 128, BT_TOK / 128), blk, 0, stream>>>(
        dh_bf, w2Td, dec_b2, nullptr, x, sums, nullptr, D_IN, H1D);

    proj_k<<<dim3(64), blk, 0, stream>>>(pooled, proj_w1, proj_b1, proj_w2, proj_b2, nproj);
    sim_k<<<dim3(64), blk, 0, stream>>>(nproj, rowterm);
    final_k<<<dim3(1), dim3(64), 0, stream>>>(rowterm, sums, out + BT_TOK);
}

// Round 7
// 786.498 us; speedup vs baseline: 1.1571x; 1.1555x over previous
//
#include <hip/hip_runtime.h>
#include <math.h>

#define BT_TOK 32768
#define D_IN   1024
#define H1D    768
#define H2D    512
#define KCB    512

typedef _Float16 f16;
typedef _Float16 half8v __attribute__((ext_vector_type(8)));
typedef float f32x4 __attribute__((ext_vector_type(4)));

#define GLDS16(g, l) \
    __builtin_amdgcn_global_load_lds((const __attribute__((address_space(1))) void*)(g), \
                                     (__attribute__((address_space(3))) void*)(l), 16, 0, 0)

// split convention: hi = f16(v), lo = f16((v-hi)*2048); v ~= hi + lo/2048
__device__ __forceinline__ void splitf(float v, f16& h, f16& l) {
    h = (f16)v;
    l = (f16)((v - (float)h) * 2048.f);
}

// ---------------------------------------------------------------------------
// Split-FP16 MFMA GEMM: 16x16x32 frags, BK=64 (two K32 sub-buffers), 128x128
// block, 2x2 waves x (4x4 16-tiles), 3 MFMAs per frag pair (hh, hl, lh).
// LDS row layout: [kk][row 0..127][32 f16 = 64 B], GLDS lane-order compatible.
// ASPLIT: A fp32 [M][Kd], split in-kernel (GEMM1).
// EPI 0: +bias -> f16 pair. 1: VQ tile-argmin. 2: +bias,relu -> f16 pair.
// EPI 3: +bias -> fp32.
// ---------------------------------------------------------------------------
template<int EPI, bool ASPLIT>
__global__ __launch_bounds__(256, 2) void sgemm_k(
    const float* __restrict__ Af,
    const f16* __restrict__ Ah, const f16* __restrict__ Al,
    const f16* __restrict__ Bh, const f16* __restrict__ Bl,
    const float* __restrict__ bias,
    f16* __restrict__ Ch, f16* __restrict__ Cl,
    float* __restrict__ Cf,
    const float* __restrict__ cnorm,
    float* __restrict__ cand_v, int* __restrict__ cand_i,
    int N, int Kd)
{
    __shared__ __align__(16) f16 sAh[2 * 128 * 32];
    __shared__ __align__(16) f16 sAl[2 * 128 * 32];
    __shared__ __align__(16) f16 sBh[2 * 128 * 32];
    __shared__ __align__(16) f16 sBl[2 * 128 * 32];

    const int t = threadIdx.x;
    const int lane = t & 63, wave = t >> 6;
    const int wm = wave & 1, wn = wave >> 1;
    const int row0 = blockIdx.y * 128, col0 = blockIdx.x * 128;

    f32x4 acc_h[4][4], acc_l[4][4];
#pragma unroll
    for (int i = 0; i < 4; ++i)
#pragma unroll
        for (int j = 0; j < 4; ++j) {
            acc_h[i][j] = (f32x4){0.f, 0.f, 0.f, 0.f};
            acc_l[i][j] = (f32x4){0.f, 0.f, 0.f, 0.f};
        }

    // GLDS staging: instr (kk,j2) covers rows j2*64 + wave*16 + (lane>>2),
    // chunk (lane&3); LDS dst = kk*8192 + j2*4096 + wave*1024 + lane*16
    const int srow = wave * 16 + (lane >> 2);
    const int scol = (lane & 3) * 8;

    const f16* gBh = Bh + (size_t)(col0 + srow) * Kd + scol;
    const f16* gBl = Bl + (size_t)(col0 + srow) * Kd + scol;
    const f16* gAh = nullptr; const f16* gAl = nullptr;
    const float* gx = nullptr;
    int xrb = 0;
    if (ASPLIT) {
        const int xr = t >> 1, xkk = t & 1;
        gx = Af + (size_t)(row0 + xr) * Kd + xkk * 32;
        xrb = xkk * 8192 + xr * 64;
    } else {
        gAh = Ah + (size_t)(row0 + srow) * Kd + scol;
        gAl = Al + (size_t)(row0 + srow) * Kd + scol;
    }

    const int fr = lane & 15;
    const int fko = (lane >> 4) * 16;   // byte offset of 16-B chunk in 64-B row

    for (int k0 = 0; k0 < Kd; k0 += 64) {
        if (ASPLIT) {
            const float4* gp = (const float4*)(gx + k0);
#pragma unroll
            for (int c = 0; c < 4; ++c) {
                const float4 f0 = gp[c * 2];
                const float4 f1 = gp[c * 2 + 1];
                const float fv[8] = {f0.x, f0.y, f0.z, f0.w, f1.x, f1.y, f1.z, f1.w};
                f16 hv[8] __attribute__((aligned(16)));
                f16 lv[8] __attribute__((aligned(16)));
#pragma unroll
                for (int i = 0; i < 8; ++i) splitf(fv[i], hv[i], lv[i]);
                *(half8v*)((char*)sAh + xrb + c * 16) = *(half8v*)hv;
                *(half8v*)((char*)sAl + xrb + c * 16) = *(half8v*)lv;
            }
        }
#pragma unroll
        for (int kk = 0; kk < 2; ++kk)
#pragma unroll
            for (int j2 = 0; j2 < 2; ++j2) {
                const size_t go = (size_t)j2 * 64 * Kd + kk * 32 + k0;
                const int lo = kk * 8192 + j2 * 4096 + wave * 1024;
                if (!ASPLIT) {
                    GLDS16(gAh + go, (char*)sAh + lo);
                    GLDS16(gAl + go, (char*)sAl + lo);
                }
                GLDS16(gBh + go, (char*)sBh + lo);
                GLDS16(gBl + go, (char*)sBl + lo);
            }
        __syncthreads();

#pragma unroll
        for (int kk = 0; kk < 2; ++kk) {
            half8v fah[4], fal[4];
#pragma unroll
            for (int mi = 0; mi < 4; ++mi) {
                const int ao = kk * 8192 + (wm * 64 + mi * 16 + fr) * 64 + fko;
                fah[mi] = *(const half8v*)((char*)sAh + ao);
                fal[mi] = *(const half8v*)((char*)sAl + ao);
            }
#pragma unroll
            for (int ni = 0; ni < 4; ++ni) {
                const int bo = kk * 8192 + (wn * 64 + ni * 16 + fr) * 64 + fko;
                const half8v fbh = *(const half8v*)((char*)sBh + bo);
                const half8v fbl = *(const half8v*)((char*)sBl + bo);
#pragma unroll
                for (int mi = 0; mi < 4; ++mi) {
                    acc_h[mi][ni] = __builtin_amdgcn_mfma_f32_16x16x32_f16(
                        fah[mi], fbh, acc_h[mi][ni], 0, 0, 0);
                    acc_l[mi][ni] = __builtin_amdgcn_mfma_f32_16x16x32_f16(
                        fah[mi], fbl, acc_l[mi][ni], 0, 0, 0);
                    acc_l[mi][ni] = __builtin_amdgcn_mfma_f32_16x16x32_f16(
                        fal[mi], fbh, acc_l[mi][ni], 0, 0, 0);
                }
            }
        }
        __syncthreads();
    }

    const int cR = (lane >> 4) * 4;   // C/D: row = quad*4 + reg, col = lane&15
    const int cC = lane & 15;

    if (EPI == 0 || EPI == 2 || EPI == 3) {
#pragma unroll
        for (int ni = 0; ni < 4; ++ni) {
            const int col = col0 + wn * 64 + ni * 16 + cC;
            const float bb = bias[col];
#pragma unroll
            for (int mi = 0; mi < 4; ++mi)
#pragma unroll
                for (int r = 0; r < 4; ++r) {
                    const size_t row = row0 + wm * 64 + mi * 16 + cR + r;
                    float v = acc_h[mi][ni][r] + acc_l[mi][ni][r] * (1.f / 2048.f) + bb;
                    if (EPI == 2) v = fmaxf(v, 0.f);
                    if (EPI == 3) {
                        Cf[row * N + col] = v;
                    } else {
                        f16 vh, vl;
                        splitf(v, vh, vl);
                        Ch[row * N + col] = vh;
                        Cl[row * N + col] = vl;
                    }
                }
        }
    } else {  // EPI == 1: VQ tile argmin
#pragma unroll
        for (int mi = 0; mi < 4; ++mi)
#pragma unroll
            for (int r = 0; r < 4; ++r) {
                float bestv = 1e30f;
                int besti = 0;
#pragma unroll
                for (int ni = 0; ni < 4; ++ni) {
                    const int col = col0 + wn * 64 + ni * 16 + cC;
                    const float v = cnorm[col]
                        - 2.f * (acc_h[mi][ni][r] + acc_l[mi][ni][r] * (1.f / 2048.f));
                    if (v < bestv || (v == bestv && col < besti)) { bestv = v; besti = col; }
                }
#pragma unroll
                for (int m = 1; m < 16; m <<= 1) {
                    const float ov = __shfl_xor(bestv, m);
                    const int oi = __shfl_xor(besti, m);
                    if (ov < bestv || (ov == bestv && oi < besti)) { bestv = ov; besti = oi; }
                }
                if (cC == 0) {
                    const size_t row = row0 + wm * 64 + mi * 16 + cR + r;
                    cand_v[row * 8 + blockIdx.x * 2 + wn] = bestv;
                    cand_i[row * 8 + blockIdx.x * 2 + wn] = besti;
                }
            }
    }
}

// ---------------------------------------------------------------------------
// Fused prep: enc weight splits^T, codebook split, dec weight splits^T,
// codebook row norms, sums init. One launch.
// ---------------------------------------------------------------------------
__global__ __launch_bounds__(256) void prep_k(
    const float* __restrict__ enc_w1, f16* __restrict__ w1h, f16* __restrict__ w1l,
    const float* __restrict__ enc_w2, f16* __restrict__ w2h, f16* __restrict__ w2l,
    const float* __restrict__ codebook, f16* __restrict__ cbh, f16* __restrict__ cbl,
    const float* __restrict__ dec_w1, f16* __restrict__ dw1h, f16* __restrict__ dw1l,
    const float* __restrict__ dec_w2, f16* __restrict__ dw2h, f16* __restrict__ dw2l,
    float* __restrict__ cnorm, float* __restrict__ sums)
{
    const int b = blockIdx.x;
    const int t = threadIdx.x;
    if (b < 3072) {                       // split^T enc_w1 [1024][768] -> [768][1024]
        const int i = b * 256 + t;
        const int n = i >> 10, k = i & 1023;
        f16 h, l; splitf(enc_w1[(size_t)k * 768 + n], h, l);
        w1h[i] = h; w1l[i] = l;
    } else if (b < 4608) {                // split^T enc_w2 [768][512] -> [512][768]
        const int i = (b - 3072) * 256 + t;
        const int n = i / 768, k = i - n * 768;
        f16 h, l; splitf(enc_w2[(size_t)k * 512 + n], h, l);
        w2h[i] = h; w2l[i] = l;
    } else if (b < 5632) {                // split codebook [512][512]
        const int i = (b - 4608) * 256 + t;
        f16 h, l; splitf(codebook[i], h, l);
        cbh[i] = h; cbl[i] = l;
    } else if (b < 7168) {                // split^T dec_w1 [512][768] -> [768][512]
        const int i = (b - 5632) * 256 + t;
        const int n = i >> 9, k = i & 511;
        f16 h, l; splitf(dec_w1[(size_t)k * 768 + n], h, l);
        dw1h[i] = h; dw1l[i] = l;
    } else if (b < 10240) {               // split^T dec_w2 [768][1024] -> [1024][768]
        const int i = (b - 7168) * 256 + t;
        const int n = i / 768, k = i - n * 768;
        f16 h, l; splitf(dec_w2[(size_t)k * 1024 + n], h, l);
        dw2h[i] = h; dw2l[i] = l;
    } else if (b < 10368) {               // codebook row sum-squares
        const int lane = t & 63, wid = t >> 6;
        const size_t row = (size_t)(b - 10240) * 4 + wid;
        const float* p = codebook + row * 512;
        float s = 0.f;
#pragma unroll
        for (int e = 0; e < 8; ++e) { const float v = p[lane + e * 64]; s = fmaf(v, v, s); }
#pragma unroll
        for (int m = 1; m < 64; m <<= 1) s += __shfl_xor(s, m);
        if (lane == 0) cnorm[row] = s;
    } else {                              // init loss accumulators
        if (t < 2) sums[t] = 0.f;
    }
}

// ---------------------------------------------------------------------------
// LayerNorm + ReLU on f16 hi/lo pair (in place), fp32 math, vectorized.
// ---------------------------------------------------------------------------
template<int H, bool ENORM>
__global__ __launch_bounds__(256) void ln_pair_k(
    f16* __restrict__ hi, f16* __restrict__ lo, const float* __restrict__ g,
    const float* __restrict__ b, float* __restrict__ enorm)
{
    constexpr int NCH = H / 8;
    constexpr int MAXC = (NCH + 63) / 64;
    const int lane = threadIdx.x & 63;
    const int wid = threadIdx.x >> 6;
    const size_t row = (size_t)blockIdx.x * 4 + wid;
    f16* ph = hi + row * H;
    f16* pl = lo + row * H;

    float h[MAXC * 8];
    float s = 0.f;
#pragma unroll
    for (int e = 0; e < MAXC; ++e) {
        const int c = lane + e * 64;
        if ((NCH % 64 == 0) || c < NCH) {
            const half8v vh = *(const half8v*)(ph + c * 8);
            const half8v vl = *(const half8v*)(pl + c * 8);
#pragma unroll
            for (int j = 0; j < 8; ++j) {
                h[e * 8 + j] = (float)vh[j] + (float)vl[j] * (1.f / 2048.f);
                s += h[e * 8 + j];
            }
        }
    }
#pragma unroll
    for (int m = 1; m < 64; m <<= 1) s += __shfl_xor(s, m);
    const float mu = s * (1.f / H);

    float vs = 0.f;
#pragma unroll
    for (int e = 0; e < MAXC; ++e) {
        const int c = lane + e * 64;
        if ((NCH % 64 == 0) || c < NCH) {
#pragma unroll
            for (int j = 0; j < 8; ++j) {
                const float d = h[e * 8 + j] - mu;
                vs = fmaf(d, d, vs);
            }
        }
    }
#pragma unroll
    for (int m = 1; m < 64; m <<= 1) vs += __shfl_xor(vs, m);
    const float rstd = rsqrtf(vs * (1.f / H) + 1e-5f);

    float q = 0.f;
#pragma unroll
    for (int e = 0; e < MAXC; ++e) {
        const int c = lane + e * 64;
        if ((NCH % 64 == 0) || c < NCH) {
            f16 oh[8] __attribute__((aligned(16)));
            f16 ol[8] __attribute__((aligned(16)));
#pragma unroll
            for (int j = 0; j < 8; ++j) {
                float o = (h[e * 8 + j] - mu) * rstd * g[c * 8 + j] + b[c * 8 + j];
                o = fmaxf(o, 0.f);
                splitf(o, oh[j], ol[j]);
                q = fmaf(o, o, q);
            }
            *(half8v*)(ph + c * 8) = *(half8v*)oh;
            *(half8v*)(pl + c * 8) = *(half8v*)ol;
        }
    }
    if (ENORM) {
#pragma unroll
        for (int m = 1; m < 64; m <<= 1) q += __shfl_xor(q, m);
        if (lane == 0) enorm[row] = q;
    }
}

__global__ __launch_bounds__(256) void vq_reduce_k(
    const float* __restrict__ cand_v, const int* __restrict__ cand_i,
    const float* __restrict__ enorm, float* __restrict__ out_idx_f,
    int* __restrict__ out_idx, float* __restrict__ commit_sum, int ntiles)
{
    const int tid = threadIdx.x;
    const int m = blockIdx.x * 256 + tid;
    float bv = cand_v[(size_t)m * ntiles];
    int bi = cand_i[(size_t)m * ntiles];
    for (int t = 1; t < ntiles; ++t) {
        const float v = cand_v[(size_t)m * ntiles + t];
        const int i = cand_i[(size_t)m * ntiles + t];
        if (v < bv || (v == bv && i < bi)) { bv = v; bi = i; }
    }
    out_idx_f[m] = (float)bi;
    out_idx[m] = bi;
    const float d2 = enorm[m] + bv;

    __shared__ float red[256];
    red[tid] = d2;
    __syncthreads();
    for (int s = 128; s > 0; s >>= 1) {
        if (tid < s) red[tid] += red[tid + s];
        __syncthreads();
    }
    if (tid == 0) atomicAdd(commit_sum, red[0]);
}

// recon: sum((V[idx[m]] - x[m])^2) over 8 tokens per block
__global__ __launch_bounds__(256) void recon_k(
    const int* __restrict__ idx, const float* __restrict__ V,
    const float* __restrict__ x, float* __restrict__ sum)
{
    const int t = threadIdx.x;
    float ls = 0.f;
#pragma unroll
    for (int tt = 0; tt < 8; ++tt) {
        const int m = blockIdx.x * 8 + tt;
        const int id = idx[m];
        const float4 v4 = ((const float4*)(V + (size_t)id * D_IN))[t];
        const float4 x4 = ((const float4*)(x + (size_t)m * D_IN))[t];
        const float d0 = v4.x - x4.x, d1 = v4.y - x4.y;
        const float d2 = v4.z - x4.z, d3 = v4.w - x4.w;
        ls = fmaf(d0, d0, ls); ls = fmaf(d1, d1, ls);
        ls = fmaf(d2, d2, ls); ls = fmaf(d3, d3, ls);
    }
    __shared__ float red[256];
    red[t] = ls;
    __syncthreads();
    for (int s = 128; s > 0; s >>= 1) {
        if (t < s) red[t] += red[t + s];
        __syncthreads();
    }
    if (t == 0) atomicAdd(sum, red[0]);
}

__global__ __launch_bounds__(256) void pooled_k(const int* __restrict__ idx,
                                                const float* __restrict__ cb,
                                                float* __restrict__ pooled)
{
    const int b = blockIdx.x;
    const int d = threadIdx.x;
    float a0 = 0.f, a1 = 0.f;
    for (int t = 0; t < 512; ++t) {
        const int id = idx[b * 512 + t];
        a0 += cb[(size_t)id * 512 + d];
        a1 += cb[(size_t)id * 512 + d + 256];
    }
    pooled[b * 512 + d] = a0 * (1.f / 512.f);
    pooled[b * 512 + d + 256] = a1 * (1.f / 512.f);
}

__global__ __launch_bounds__(256) void proj_k(
    const float* __restrict__ pooled, const float* __restrict__ w1,
    const float* __restrict__ b1, const float* __restrict__ w2,
    const float* __restrict__ b2, float* __restrict__ nproj)
{
    __shared__ float sp[512];
    __shared__ float sh[256];
    __shared__ float red[128];
    const int b = blockIdx.x, tid = threadIdx.x;
    sp[tid] = pooled[b * 512 + tid];
    sp[tid + 256] = pooled[b * 512 + tid + 256];
    __syncthreads();

    float acc = b1[tid];
    for (int k = 0; k < 512; ++k) acc = fmaf(sp[k], w1[k * 256 + tid], acc);
    sh[tid] = fmaxf(acc, 0.f);
    __syncthreads();

    float p = 0.f;
    if (tid < 128) {
        p = b2[tid];
        for (int k = 0; k < 256; ++k) p = fmaf(sh[k], w2[k * 128 + tid], p);
        red[tid] = p * p;
    }
    __syncthreads();
    for (int s = 64; s > 0; s >>= 1) {
        if (tid < s) red[tid] += red[tid + s];
        __syncthreads();
    }
    if (tid < 128) {
        const float nrm = fmaxf(sqrtf(red[0]), 1e-12f);
        nproj[b * 128 + tid] = p / nrm;
    }
}

// one block per row i of the 64x64 sim matrix; log-softmax diag term
__global__ __launch_bounds__(256) void sim_k(
    const float* __restrict__ nproj, float* __restrict__ rowterm)
{
    __shared__ float ri[128];
    __shared__ float srow[64];
    const int i = blockIdx.x, t = threadIdx.x;
    if (t < 128) ri[t] = nproj[i * 128 + t];
    __syncthreads();

    const int j = t >> 2, q = t & 3;
    float d = 0.f;
    for (int k = q * 32; k < q * 32 + 32; ++k)
        d = fmaf(ri[k], nproj[j * 128 + k], d);
    d += __shfl_xor(d, 1);
    d += __shfl_xor(d, 2);
    if (q == 0) srow[j] = d * 10.f;   // / TEMP
    __syncthreads();

    if (t < 64) {
        float v = srow[t];
        float mx = v;
#pragma unroll
        for (int m = 1; m < 64; m <<= 1) mx = fmaxf(mx, __shfl_xor(mx, m));
        float e = expf(v - mx);
#pragma unroll
        for (int m = 1; m < 64; m <<= 1) e += __shfl_xor(e, m);
        if (t == 0) rowterm[i] = srow[i] - (mx + logf(e));
    }
}

__global__ __launch_bounds__(64) void final_k(
    const float* __restrict__ rowterm, const float* __restrict__ sums,
    float* __restrict__ out5)
{
    const int t = threadIdx.x;
    float c = rowterm[t];
#pragma unroll
    for (int m = 1; m < 64; m <<= 1) c += __shfl_xor(c, m);
    if (t == 0) {
        const float contr = -c / 64.f;
        const float recon = sums[0] / ((float)BT_TOK * (float)D_IN);
        const float commit = sums[1] / ((float)BT_TOK * (float)H2D);
        const float cbl = commit;
        const float total = recon * 1.0f + commit * 1.0f + cbl * 0.25f + contr * 0.5f;
        out5[0] = total;
        out5[1] = recon;
        out5[2] = commit;
        out5[3] = cbl;
        out5[4] = contr;
    }
}

extern "C" void kernel_launch(void* const* d_in, const int* in_sizes, int n_in,
                              void* d_out, int out_size, void* d_ws, size_t ws_size,
                              hipStream_t stream)
{
    const float* x       = (const float*)d_in[0];
    const float* enc_w1  = (const float*)d_in[1];
    const float* enc_b1  = (const float*)d_in[2];
    const float* ln1_g   = (const float*)d_in[3];
    const float* ln1_b   = (const float*)d_in[4];
    const float* enc_w2  = (const float*)d_in[5];
    const float* enc_b2  = (const float*)d_in[6];
    const float* ln2_g   = (const float*)d_in[7];
    const float* ln2_b   = (const float*)d_in[8];
    const float* codebook= (const float*)d_in[9];
    const float* dec_w1  = (const float*)d_in[10];
    const float* dec_b1  = (const float*)d_in[11];
    const float* dec_w2  = (const float*)d_in[12];
    const float* dec_b2  = (const float*)d_in[13];
    const float* proj_w1 = (const float*)d_in[14];
    const float* proj_b1 = (const float*)d_in[15];
    const float* proj_w2 = (const float*)d_in[16];
    const float* proj_b2 = (const float*)d_in[17];
    float* out = (float*)d_out;

    char* wsb = (char*)d_ws;
    size_t off = 0;
    auto alloc = [&](size_t bytes) {
        void* p = wsb + off;
        off += (bytes + 255) & ~(size_t)255;
        return p;
    };

    f16* h1h  = (f16*)alloc((size_t)BT_TOK * H1D * 2);
    f16* h1l  = (f16*)alloc((size_t)BT_TOK * H1D * 2);
    f16* ench = (f16*)alloc((size_t)BT_TOK * H2D * 2);
    f16* encl = (f16*)alloc((size_t)BT_TOK * H2D * 2);
    f16* w1h  = (f16*)alloc((size_t)H1D * D_IN * 2);
    f16* w1l  = (f16*)alloc((size_t)H1D * D_IN * 2);
    f16* w2h  = (f16*)alloc((size_t)H2D * H1D * 2);
    f16* w2l  = (f16*)alloc((size_t)H2D * H1D * 2);
    f16* cbh  = (f16*)alloc((size_t)KCB * H2D * 2);
    f16* cbl  = (f16*)alloc((size_t)KCB * H2D * 2);
    f16* dw1h = (f16*)alloc((size_t)H1D * H2D * 2);   // [768][512]
    f16* dw1l = (f16*)alloc((size_t)H1D * H2D * 2);
    f16* dw2h = (f16*)alloc((size_t)D_IN * H1D * 2);  // [1024][768]
    f16* dw2l = (f16*)alloc((size_t)D_IN * H1D * 2);
    f16* Uh   = (f16*)alloc((size_t)KCB * H1D * 2);   // relu(cb@W1+b1) pair
    f16* Ul   = (f16*)alloc((size_t)KCB * H1D * 2);
    float* Vf = (float*)alloc((size_t)KCB * D_IN * 4); // per-code decoded rows
    float* cnorm  = (float*)alloc(KCB * 4);
    float* enorm  = (float*)alloc(BT_TOK * 4);
    float* cand_v = (float*)alloc((size_t)BT_TOK * 8 * 4);
    int*   cand_i = (int*)alloc((size_t)BT_TOK * 8 * 4);
    int*   idxbuf = (int*)alloc(BT_TOK * 4);
    float* pooled = (float*)alloc(64 * 512 * 4);
    float* nproj  = (float*)alloc(64 * 128 * 4);
    float* rowterm= (float*)alloc(64 * 4);
    float* sums   = (float*)alloc(2 * 4);

    const dim3 blk(256);

    // prep: all weight splits + cnorm + sums init
    prep_k<<<dim3(10369), blk, 0, stream>>>(
        enc_w1, w1h, w1l, enc_w2, w2h, w2l, codebook, cbh, cbl,
        dec_w1, dw1h, dw1l, dec_w2, dw2h, dw2l, cnorm, sums);

    // per-code decoder tables (decoder input has only 512 distinct values):
    // U = relu(cb @ dec_w1 + b1)  [512 x 768];  V = U @ dec_w2 + b2 [512 x 1024]
    sgemm_k<2, false><<<dim3(H1D / 128, KCB / 128), blk, 0, stream>>>(
        nullptr, cbh, cbl, dw1h, dw1l, dec_b1, Uh, Ul, nullptr,
        nullptr, nullptr, nullptr, H1D, H2D);
    sgemm_k<3, false><<<dim3(D_IN / 128, KCB / 128), blk, 0, stream>>>(
        nullptr, Uh, Ul, dw2h, dw2l, dec_b2, nullptr, nullptr, Vf,
        nullptr, nullptr, nullptr, D_IN, H1D);

    // encoder layer 1 (in-kernel x split): h1 = x @ enc_w1 + b1
    sgemm_k<0, true><<<dim3(H1D / 128, BT_TOK / 128), blk, 0, stream>>>(
        x, nullptr, nullptr, w1h, w1l, enc_b1, h1h, h1l, nullptr,
        nullptr, nullptr, nullptr, H1D, D_IN);
    ln_pair_k<H1D, false><<<dim3(BT_TOK / 4), blk, 0, stream>>>(h1h, h1l, ln1_g, ln1_b, nullptr);

    // encoder layer 2: enc = h1 @ enc_w2 + b2
    sgemm_k<0, false><<<dim3(H2D / 128, BT_TOK / 128), blk, 0, stream>>>(
        nullptr, h1h, h1l, w2h, w2l, enc_b2, ench, encl, nullptr,
        nullptr, nullptr, nullptr, H2D, H1D);
    ln_pair_k<H2D, true><<<dim3(BT_TOK / 4), blk, 0, stream>>>(ench, encl, ln2_g, ln2_b, enorm);

    // VQ scores + tile argmin (fp32-equivalent via split)
    sgemm_k<1, false><<<dim3(KCB / 128, BT_TOK / 128), blk, 0, stream>>>(
        nullptr, ench, encl, cbh, cbl, nullptr, nullptr, nullptr, nullptr,
        cnorm, cand_v, cand_i, KCB, H2D);
    vq_reduce_k<<<dim3(BT_TOK / 256), blk, 0, stream>>>(
        cand_v, cand_i, enorm, out, idxbuf, sums + 1, 8);

    // recon loss via per-code decoded table (exact decoder collapse)
    recon_k<<<dim3(BT_TOK / 8), blk, 0, stream>>>(idxbuf, Vf, x, sums);

    pooled_k<<<dim3(64), blk, 0, stream>>>(idxbuf, codebook, pooled);
    proj_k<<<dim3(64), blk, 0, stream>>>(pooled, proj_w1, proj_b1, proj_w2, proj_b2, nproj);
    sim_k<<<dim3(64), blk, 0, stream>>>(nproj, rowterm);
    final_k<<<dim3(1), dim3(64), 0, stream>>>(rowterm, sums, out + BT_TOK);
}